// Round 1
// baseline (4763.490 us; speedup 1.0000x reference)
//
#include <hip/hip_runtime.h>
#include <cmath>

// CfC encoder: 3-layer liquid-NN recurrence, B=512, K=64 steps.
// Strategy: split-bf16 (hi/lo) MFMA GEMMs, 3 products per pair for fp32-class
// accuracy. Layers software-pipelined: one launch runs L0(s), L1(s-1), L2(s-2)
// concurrently as block-role partitions (no inter-block deps within a launch).

typedef __attribute__((ext_vector_type(8))) short short8;
typedef __attribute__((ext_vector_type(4))) float f32x4;

#define DEVINL __device__ __forceinline__

DEVINL short f2bf(float x) {            // fp32 -> bf16 RNE
  union { float f; unsigned u; } a; a.f = x;
  unsigned r = a.u + 0x7fffu + ((a.u >> 16) & 1u);
  return (short)(r >> 16);
}
DEVINL float bf2f(short s) {
  union { unsigned u; float f; } a; a.u = ((unsigned)(unsigned short)s) << 16;
  return a.f;
}

// load 8 consecutive fp32, split into bf16 hi/lo fragments
DEVINL void split_f32x8(const float* p, short8& hi, short8& lo) {
  const f32x4* q = (const f32x4*)p;
  f32x4 v0 = q[0], v1 = q[1];
#pragma unroll
  for (int j = 0; j < 4; ++j) {
    short h0 = f2bf(v0[j]); hi[j] = h0; lo[j] = f2bf(v0[j] - bf2f(h0));
    short h1 = f2bf(v1[j]); hi[j + 4] = h1; lo[j + 4] = f2bf(v1[j] - bf2f(h1));
  }
}

struct Params {
  const float* base;    // (512,64,256) fp32
  const float* visual;  // (512,64,512) fp32
  const short *w0h, *w0l, *w1h, *w1l, *w2h, *w2l;   // [gate][n][k] bf16 planes
  const float *b0f1, *b0f2, *b0ta, *b0tb;
  const float *b1f1, *b1f2, *b1ta, *b1tb;
  const float *b2f1, *b2f2, *b2ta, *b2tb;
  short *h0h0, *h0l0, *h0h1, *h0l1;   // h state ping-pong, hi/lo planes
  short *h1h0, *h1l0, *h1h1, *h1l1;
  short *h2h0, *h2l0, *h2h1, *h2l1;
  float* out;                          // d_out (512,64) fp32, written at t=63
};

// One CfC layer tile: wave computes 32 batch rows x 16 neurons x 4 gates.
// Block = 4 waves stacked along M (share B-fragments via L1).
template <int L>
DEVINL void run_layer(const Params& p, int t, int mt, int nt) {
  constexpr int HH = (L == 0) ? 512 : ((L == 1) ? 256 : 64);
  constexpr int K  = (L == 0) ? 1280 : ((L == 1) ? 768 : 320);
  constexpr int NC = K / 32;

  const int lane = threadIdx.x & 63;
  const int wv   = threadIdx.x >> 6;
  const int lr   = lane & 15;
  const int lq   = lane >> 4;
  const int m_base = mt * 128 + wv * 32;
  const int n0 = nt * 16;
  const int rd = t & 1;                 // read-prev buffer index; write = 1-rd

  const short *wh, *wl, *pah = nullptr, *pal = nullptr, *hph, *hpl;
  short *oh, *ol;
  const float *bf1p, *bf2p, *btap, *btbp;
  if constexpr (L == 0) {
    wh = p.w0h; wl = p.w0l;
    hph = rd ? p.h0h1 : p.h0h0;  hpl = rd ? p.h0l1 : p.h0l0;
    oh  = rd ? p.h0h0 : p.h0h1;  ol  = rd ? p.h0l0 : p.h0l1;
    bf1p = p.b0f1; bf2p = p.b0f2; btap = p.b0ta; btbp = p.b0tb;
  } else if constexpr (L == 1) {
    wh = p.w1h; wl = p.w1l;
    pah = rd ? p.h0h0 : p.h0h1;  pal = rd ? p.h0l0 : p.h0l1;  // h0(t) = L0's write-buf at t
    hph = rd ? p.h1h1 : p.h1h0;  hpl = rd ? p.h1l1 : p.h1l0;
    oh  = rd ? p.h1h0 : p.h1h1;  ol  = rd ? p.h1l0 : p.h1l1;
    bf1p = p.b1f1; bf2p = p.b1f2; btap = p.b1ta; btbp = p.b1tb;
  } else {
    wh = p.w2h; wl = p.w2l;
    pah = rd ? p.h1h0 : p.h1h1;  pal = rd ? p.h1l0 : p.h1l1;
    hph = rd ? p.h2h1 : p.h2h0;  hpl = rd ? p.h2l1 : p.h2l0;
    oh  = rd ? p.h2h0 : p.h2h1;  ol  = rd ? p.h2l0 : p.h2l1;
    bf1p = p.b2f1; bf2p = p.b2f2; btap = p.b2ta; btbp = p.b2tb;
  }

  f32x4 zz = {0.f, 0.f, 0.f, 0.f};
  f32x4 acc[2][4];
#pragma unroll
  for (int s = 0; s < 2; ++s)
#pragma unroll
    for (int g = 0; g < 4; ++g) acc[s][g] = zz;

  const int kfrag = lq * 8;

#pragma unroll 2
  for (int c = 0; c < NC; ++c) {
    const int kk = c * 32 + kfrag;
    // B fragments: weights, lane lr = neuron n, 8 contiguous k
    short8 bh[4], bl[4];
    {
      const short* wb0 = wh + (n0 + lr) * K + kk;
      const short* wb1 = wl + (n0 + lr) * K + kk;
#pragma unroll
      for (int g = 0; g < 4; ++g) {
        bh[g] = *(const short8*)(wb0 + g * (HH * K));
        bl[g] = *(const short8*)(wb1 + g * (HH * K));
      }
    }
    // A fragments: lane lr = batch row (within 16-row set), 8 contiguous k
    short8 ah[2], al[2];
#pragma unroll
    for (int s = 0; s < 2; ++s) {
      const int m = m_base + s * 16 + lr;
      if constexpr (L == 0) {
        if (c < 8) {
          split_f32x8(p.base + ((m * 64 + t) * 256 + kk), ah[s], al[s]);
        } else if (c < 24) {
          split_f32x8(p.visual + ((m * 64 + t) * 512 + (kk - 256)), ah[s], al[s]);
        } else {
          ah[s] = *(const short8*)(hph + m * 512 + (kk - 768));
          al[s] = *(const short8*)(hpl + m * 512 + (kk - 768));
        }
      } else if constexpr (L == 1) {
        if (c < 16) {
          ah[s] = *(const short8*)(pah + m * 512 + kk);
          al[s] = *(const short8*)(pal + m * 512 + kk);
        } else {
          ah[s] = *(const short8*)(hph + m * 256 + (kk - 512));
          al[s] = *(const short8*)(hpl + m * 256 + (kk - 512));
        }
      } else {
        if (c < 8) {
          ah[s] = *(const short8*)(pah + m * 256 + kk);
          al[s] = *(const short8*)(pal + m * 256 + kk);
        } else {
          ah[s] = *(const short8*)(hph + m * 64 + (kk - 256));
          al[s] = *(const short8*)(hpl + m * 64 + (kk - 256));
        }
      }
    }
    // 3-term split MFMA: AhiBhi + AloBhi + AhiBlo (~2^-16 rel error)
#pragma unroll
    for (int s = 0; s < 2; ++s)
#pragma unroll
      for (int g = 0; g < 4; ++g) {
        acc[s][g] = __builtin_amdgcn_mfma_f32_16x16x32_bf16(ah[s], bh[g], acc[s][g], 0, 0, 0);
        acc[s][g] = __builtin_amdgcn_mfma_f32_16x16x32_bf16(al[s], bh[g], acc[s][g], 0, 0, 0);
        acc[s][g] = __builtin_amdgcn_mfma_f32_16x16x32_bf16(ah[s], bl[g], acc[s][g], 0, 0, 0);
      }
  }

  // Epilogue: C/D layout col=lane&15 (n), row=(lane>>4)*4+r (batch)
  const int n = n0 + lr;
  const float bff1 = bf1p[n], bff2 = bf2p[n], bta = btap[n], btb = btbp[n];
#pragma unroll
  for (int s = 0; s < 2; ++s) {
    const int mrow = m_base + s * 16 + lq * 4;
#pragma unroll
    for (int r = 0; r < 4; ++r) {
      float vf1 = acc[s][0][r] + bff1;
      float vf2 = acc[s][1][r] + bff2;
      float vt  = (acc[s][2][r] + bta) + (acc[s][3][r] + btb);  // ts = 1.0
      float ff1 = tanhf(vf1);
      float ff2 = tanhf(vf2);
      float ti  = 1.0f / (1.0f + __expf(-vt));
      float hv  = ff1 + ti * (ff2 - ff1);
      const int row = mrow + r;
      short hh = f2bf(hv);
      oh[row * HH + n] = hh;
      ol[row * HH + n] = f2bf(hv - bf2f(hh));
      if constexpr (L == 2) {
        if (t == 63) p.out[row * 64 + n] = hv;
      }
    }
  }
}

// Merged pipeline step s: blocks 0..127 -> L0(t=s), 128..191 -> L1(t=s-1),
// 192..207 -> L2(t=s-2). Mutually independent (L0 chain only depends on L0).
__global__ __launch_bounds__(256, 1) void cfc_merged(Params p, int s) {
  const int bid = blockIdx.x;
  if (bid < 128) {
    if (s < 64) run_layer<0>(p, s, bid >> 5, bid & 31);
  } else if (bid < 192) {
    const int t = s - 1;
    if (t >= 0 && t < 64) { const int b = bid - 128; run_layer<1>(p, t, b >> 4, b & 15); }
  } else {
    const int t = s - 2;
    if (t >= 0 && t < 64) { const int b = bid - 192; run_layer<2>(p, t, b >> 2, b & 3); }
  }
}

// mask (if non-null) applied, then split to bf16 hi/lo planes
__global__ void prep_w_kernel(const float* __restrict__ w, const float* __restrict__ mask,
                              short* __restrict__ hi, short* __restrict__ lo, int n) {
  int i = blockIdx.x * 256 + threadIdx.x;
  if (i < n) {
    float v = w[i];
    if (mask) v *= mask[i];
    short h = f2bf(v);
    hi[i] = h;
    lo[i] = f2bf(v - bf2f(h));
  }
}

__global__ void zero_kernel(unsigned* __restrict__ p, int n) {
  int i = blockIdx.x * 256 + threadIdx.x;
  if (i < n) p[i] = 0u;
}

extern "C" void kernel_launch(void* const* d_in, const int* in_sizes, int n_in,
                              void* d_out, int out_size, void* d_ws, size_t ws_size,
                              hipStream_t stream) {
  // ---- workspace layout (shorts) ----
  short* w0h = (short*)d_ws;                // 4*512*1280 = 2,621,440
  short* w0l = w0h + 2621440;
  short* w1h = w0l + 2621440;               // 4*256*768 = 786,432
  short* w1l = w1h + 786432;
  short* w2h = w1l + 786432;                // 4*64*320 = 81,920
  short* w2l = w2h + 81920;
  short* hb  = w2l + 81920;                 // h state region (contiguous, zeroed)
  short* h0h0 = hb;               short* h0l0 = h0h0 + 262144;
  short* h0h1 = h0l0 + 262144;    short* h0l1 = h0h1 + 262144;
  short* h1h0 = h0l1 + 262144;    short* h1l0 = h1h0 + 131072;
  short* h1h1 = h1l0 + 131072;    short* h1l1 = h1h1 + 131072;
  short* h2h0 = h1l1 + 131072;    short* h2l0 = h2h0 + 32768;
  short* h2h1 = h2l0 + 32768;     short* h2l1 = h2h1 + 32768;
  // total: 17,367,040 bytes

  // zero all h ping-pong buffers (poisoned 0xAA before every timed launch)
  const int h_uints = (4 * (262144 + 131072 + 32768) * 2) / 4;  // 851,968
  zero_kernel<<<(h_uints + 255) / 256, 256, 0, stream>>>((unsigned*)hb, h_uints);

  const float* F = nullptr;
  auto in = [&](int i) { return (const float*)d_in[i]; };

  // weight prep: gates [ff1,ff2,ta,tb]; mask applies to ff1/ff2 only
  // L0: w at 2,4,6,8; mask 10. plane stride 655,360
  prep_w_kernel<<<2560, 256, 0, stream>>>(in(2),  in(10), w0h + 0 * 655360, w0l + 0 * 655360, 655360);
  prep_w_kernel<<<2560, 256, 0, stream>>>(in(4),  in(10), w0h + 1 * 655360, w0l + 1 * 655360, 655360);
  prep_w_kernel<<<2560, 256, 0, stream>>>(in(6),  F,      w0h + 2 * 655360, w0l + 2 * 655360, 655360);
  prep_w_kernel<<<2560, 256, 0, stream>>>(in(8),  F,      w0h + 3 * 655360, w0l + 3 * 655360, 655360);
  // L1: w at 11,13,15,17; mask 19. plane stride 196,608
  prep_w_kernel<<<768, 256, 0, stream>>>(in(11), in(19), w1h + 0 * 196608, w1l + 0 * 196608, 196608);
  prep_w_kernel<<<768, 256, 0, stream>>>(in(13), in(19), w1h + 1 * 196608, w1l + 1 * 196608, 196608);
  prep_w_kernel<<<768, 256, 0, stream>>>(in(15), F,      w1h + 2 * 196608, w1l + 2 * 196608, 196608);
  prep_w_kernel<<<768, 256, 0, stream>>>(in(17), F,      w1h + 3 * 196608, w1l + 3 * 196608, 196608);
  // L2: w at 20,22,24,26; mask 28. plane stride 20,480
  prep_w_kernel<<<80, 256, 0, stream>>>(in(20), in(28), w2h + 0 * 20480, w2l + 0 * 20480, 20480);
  prep_w_kernel<<<80, 256, 0, stream>>>(in(22), in(28), w2h + 1 * 20480, w2l + 1 * 20480, 20480);
  prep_w_kernel<<<80, 256, 0, stream>>>(in(24), F,      w2h + 2 * 20480, w2l + 2 * 20480, 20480);
  prep_w_kernel<<<80, 256, 0, stream>>>(in(26), F,      w2h + 3 * 20480, w2l + 3 * 20480, 20480);

  Params p;
  p.base = in(0); p.visual = in(1);
  p.w0h = w0h; p.w0l = w0l; p.w1h = w1h; p.w1l = w1l; p.w2h = w2h; p.w2l = w2l;
  p.b0f1 = in(3);  p.b0f2 = in(5);  p.b0ta = in(7);  p.b0tb = in(9);
  p.b1f1 = in(12); p.b1f2 = in(14); p.b1ta = in(16); p.b1tb = in(18);
  p.b2f1 = in(21); p.b2f2 = in(23); p.b2ta = in(25); p.b2tb = in(27);
  p.h0h0 = h0h0; p.h0l0 = h0l0; p.h0h1 = h0h1; p.h0l1 = h0l1;
  p.h1h0 = h1h0; p.h1l0 = h1l0; p.h1h1 = h1h1; p.h1l1 = h1l1;
  p.h2h0 = h2h0; p.h2l0 = h2l0; p.h2h1 = h2h1; p.h2l1 = h2l1;
  p.out = (float*)d_out;

  // 66 pipelined steps: L0 runs s=0..63, L1 s=1..64 (t=s-1), L2 s=2..65 (t=s-2)
  for (int s = 0; s < 66; ++s) {
    cfc_merged<<<208, 256, 0, stream>>>(p, s);
  }
}

// Round 2
// 3163.535 us; speedup vs baseline: 1.5057x; 1.5057x over previous
//
#include <hip/hip_runtime.h>
#include <cmath>

// CfC encoder: 3-layer liquid-NN recurrence, B=512, K=64 steps, fp32 io.
// R2: fp16 2-term split MFMA (A = hi+lo activations, B = fp16 weights),
// x-part of L0 hoisted off the serial path via a per-step pipelined pre-GEMM.
// 5 roles per launch: XPREP(t+2) | XGEMM(t+1) | L0rec(t) | L1(t-1) | L2(t-2).

typedef __attribute__((ext_vector_type(8))) _Float16 half8;
typedef __attribute__((ext_vector_type(4))) float f32x4;

#define DEVINL __device__ __forceinline__

struct Params {
  const float* base;    // (512,64,256)
  const float* visual;  // (512,64,512)
  const _Float16 *w0, *w1, *w2;   // [gate][n][K] fp16, K = 1280/768/320
  const float *b0f1,*b0f2,*b0ta,*b0tb;
  const float *b1f1,*b1f2,*b1ta,*b1tb;
  const float *b2f1,*b2f2,*b2ta,*b2tb;
  _Float16 *xh0,*xl0,*xh1,*xl1;   // x split planes, double buffer (512*768)
  float *xacc0,*xacc1;            // x pre-GEMM out, double buffer (512*2048) fp32
  _Float16 *h0h0,*h0h1,*h0l0,*h0l1;   // h planes: [buf = t&1]
  _Float16 *h1h0,*h1h1,*h1l0,*h1l1;
  _Float16 *h2h0,*h2h1,*h2l0,*h2l1;
  float* out;
};

// ---- role: split x(t) fp32 -> fp16 hi/lo planes (buf t&1) ----
DEVINL void run_xprep(const Params& p, int t, int b /*0..23*/) {
  _Float16* xh = (t & 1) ? p.xh1 : p.xh0;
  _Float16* xl = (t & 1) ? p.xl1 : p.xl0;
  int tid = b * 256 + threadIdx.x;            // 6144 threads
  for (int i = tid; i < 49152; i += 6144) {   // 512 rows * 96 groups of 8
    int m = i / 96;
    int k = (i - m * 96) * 8;
    const float* src = (k < 256) ? (p.base + (m * 64 + t) * 256 + k)
                                 : (p.visual + (m * 64 + t) * 512 + (k - 256));
    const f32x4* q = (const f32x4*)src;
    f32x4 v0 = q[0], v1 = q[1];
    half8 hh, ll;
#pragma unroll
    for (int j = 0; j < 4; ++j) {
      _Float16 a = (_Float16)v0[j]; hh[j] = a;     ll[j]     = (_Float16)(v0[j] - (float)a);
      _Float16 c = (_Float16)v1[j]; hh[j + 4] = c; ll[j + 4] = (_Float16)(v1[j] - (float)c);
    }
    *(half8*)(xh + m * 768 + k) = hh;
    *(half8*)(xl + m * 768 + k) = ll;
  }
}

// ---- role: xacc(t) = x(t) @ W0x^T  (K=768 x-part of L0, all 4 gates) ----
DEVINL void run_xgemm(const Params& p, int t, int b /*0..127*/) {
  const _Float16* xh = (t & 1) ? p.xh1 : p.xh0;
  const _Float16* xl = (t & 1) ? p.xl1 : p.xl0;
  float* xacc = (t & 1) ? p.xacc1 : p.xacc0;
  const int lane = threadIdx.x & 63, wv = threadIdx.x >> 6;
  const int lr = lane & 15, lq = lane >> 4;
  const int mt = b >> 5, nt = b & 31;
  const int m_base = mt * 128 + wv * 32, n0 = nt * 16, kfrag = lq * 8;

  f32x4 zz = {0.f,0.f,0.f,0.f};
  f32x4 acc[2][4];
#pragma unroll
  for (int s = 0; s < 2; ++s)
#pragma unroll
    for (int g = 0; g < 4; ++g) acc[s][g] = zz;

#pragma unroll 2
  for (int c = 0; c < 24; ++c) {
    const int kk = c * 32 + kfrag;
    half8 bh[4];
    const _Float16* wb = p.w0 + (n0 + lr) * 1280 + kk;
#pragma unroll
    for (int g = 0; g < 4; ++g) bh[g] = *(const half8*)(wb + g * (512 * 1280));
    half8 ah[2], al[2];
#pragma unroll
    for (int s = 0; s < 2; ++s) {
      const int m = m_base + s * 16 + lr;
      ah[s] = *(const half8*)(xh + m * 768 + kk);
      al[s] = *(const half8*)(xl + m * 768 + kk);
    }
#pragma unroll
    for (int s = 0; s < 2; ++s)
#pragma unroll
      for (int g = 0; g < 4; ++g) {
        acc[s][g] = __builtin_amdgcn_mfma_f32_16x16x32_f16(ah[s], bh[g], acc[s][g], 0, 0, 0);
        acc[s][g] = __builtin_amdgcn_mfma_f32_16x16x32_f16(al[s], bh[g], acc[s][g], 0, 0, 0);
      }
  }
  const int n = n0 + lr;
#pragma unroll
  for (int s = 0; s < 2; ++s) {
    const int mrow = m_base + s * 16 + lq * 4;
#pragma unroll
    for (int g = 0; g < 4; ++g)
#pragma unroll
      for (int r = 0; r < 4; ++r)
        xacc[(mrow + r) * 2048 + g * 512 + n] = acc[s][g][r];
  }
}

// ---- role: recurrent layer step (L0 adds xacc; L1/L2 read prev-layer h) ----
template <int L>
DEVINL void run_rec(const Params& p, int t, int b) {
  constexpr int HH = (L == 0) ? 512 : ((L == 1) ? 256 : 64);
  constexpr int WK = (L == 0) ? 1280 : ((L == 1) ? 768 : 320);
  constexpr int NC = (L == 0) ? 16 : ((L == 1) ? 24 : 10);  // K chunks (rec path only for L0)

  const int lane = threadIdx.x & 63, wv = threadIdx.x >> 6;
  const int lr = lane & 15, lq = lane >> 4;
  int mt, nt;
  if constexpr (L == 0)      { mt = b >> 5; nt = b & 31; }
  else if constexpr (L == 1) { mt = b >> 4; nt = b & 15; }
  else                       { mt = b >> 2; nt = b & 3; }
  const int m_base = mt * 128 + wv * 32, n0 = nt * 16, kfrag = lq * 8;
  const int wbuf = t & 1;

  const _Float16 *wgt, *hph, *hpl, *pah = nullptr, *pal = nullptr;
  _Float16 *oh, *ol;
  const float *bf1p, *bf2p, *btap, *btbp;
  if constexpr (L == 0) {
    wgt = p.w0 + 768;  // recurrent k-range [768,1280)
    hph = wbuf ? p.h0h0 : p.h0h1;  hpl = wbuf ? p.h0l0 : p.h0l1;
    oh  = wbuf ? p.h0h1 : p.h0h0;  ol  = wbuf ? p.h0l1 : p.h0l0;
    bf1p = p.b0f1; bf2p = p.b0f2; btap = p.b0ta; btbp = p.b0tb;
  } else if constexpr (L == 1) {
    wgt = p.w1;
    pah = wbuf ? p.h0h1 : p.h0h0;  pal = wbuf ? p.h0l1 : p.h0l0;  // h0(t)
    hph = wbuf ? p.h1h0 : p.h1h1;  hpl = wbuf ? p.h1l0 : p.h1l1;  // h1(t-1)
    oh  = wbuf ? p.h1h1 : p.h1h0;  ol  = wbuf ? p.h1l1 : p.h1l0;
    bf1p = p.b1f1; bf2p = p.b1f2; btap = p.b1ta; btbp = p.b1tb;
  } else {
    wgt = p.w2;
    pah = wbuf ? p.h1h1 : p.h1h0;  pal = wbuf ? p.h1l1 : p.h1l0;  // h1(t)
    hph = wbuf ? p.h2h0 : p.h2h1;  hpl = wbuf ? p.h2l0 : p.h2l1;  // h2(t-1)
    oh  = wbuf ? p.h2h1 : p.h2h0;  ol  = wbuf ? p.h2l1 : p.h2l0;
    bf1p = p.b2f1; bf2p = p.b2f2; btap = p.b2ta; btbp = p.b2tb;
  }

  f32x4 zz = {0.f,0.f,0.f,0.f};
  f32x4 acc[2][4];
#pragma unroll
  for (int s = 0; s < 2; ++s)
#pragma unroll
    for (int g = 0; g < 4; ++g) acc[s][g] = zz;

#pragma unroll 2
  for (int c = 0; c < NC; ++c) {
    const int kk = c * 32 + kfrag;
    half8 bh[4];
    const _Float16* wb = wgt + (n0 + lr) * WK + kk;
#pragma unroll
    for (int g = 0; g < 4; ++g) bh[g] = *(const half8*)(wb + g * (HH * WK));
    half8 ah[2], al[2];
#pragma unroll
    for (int s = 0; s < 2; ++s) {
      const int m = m_base + s * 16 + lr;
      if constexpr (L == 0) {
        ah[s] = *(const half8*)(hph + m * 512 + kk);
        al[s] = *(const half8*)(hpl + m * 512 + kk);
      } else if constexpr (L == 1) {
        if (c < 16) { ah[s] = *(const half8*)(pah + m * 512 + kk);
                      al[s] = *(const half8*)(pal + m * 512 + kk); }
        else        { ah[s] = *(const half8*)(hph + m * 256 + (kk - 512));
                      al[s] = *(const half8*)(hpl + m * 256 + (kk - 512)); }
      } else {
        if (c < 8)  { ah[s] = *(const half8*)(pah + m * 256 + kk);
                      al[s] = *(const half8*)(pal + m * 256 + kk); }
        else        { ah[s] = *(const half8*)(hph + m * 64 + (kk - 256));
                      al[s] = *(const half8*)(hpl + m * 64 + (kk - 256)); }
      }
    }
#pragma unroll
    for (int s = 0; s < 2; ++s)
#pragma unroll
      for (int g = 0; g < 4; ++g) {
        acc[s][g] = __builtin_amdgcn_mfma_f32_16x16x32_f16(ah[s], bh[g], acc[s][g], 0, 0, 0);
        acc[s][g] = __builtin_amdgcn_mfma_f32_16x16x32_f16(al[s], bh[g], acc[s][g], 0, 0, 0);
      }
  }

  const float* xacc = nullptr;
  if constexpr (L == 0) xacc = (t & 1) ? p.xacc1 : p.xacc0;

  const int n = n0 + lr;
  const float bff1 = bf1p[n], bff2 = bf2p[n], bta = btap[n], btb = btbp[n];
#pragma unroll
  for (int s = 0; s < 2; ++s) {
    const int mrow = m_base + s * 16 + lq * 4;
#pragma unroll
    for (int r = 0; r < 4; ++r) {
      const int row = mrow + r;
      float a0 = acc[s][0][r], a1 = acc[s][1][r], a2 = acc[s][2][r], a3 = acc[s][3][r];
      if constexpr (L == 0) {
        const float* xb = xacc + row * 2048 + n;
        a0 += xb[0]; a1 += xb[512]; a2 += xb[1024]; a3 += xb[1536];
      }
      float vf1 = a0 + bff1;
      float vf2 = a1 + bff2;
      float vt  = (a2 + bta) + (a3 + btb);     // ts = 1.0
      float ff1 = tanhf(vf1);
      float ff2 = tanhf(vf2);
      float ti  = 1.0f / (1.0f + __expf(-vt));
      float hv  = ff1 + ti * (ff2 - ff1);
      _Float16 hh = (_Float16)hv;
      oh[row * HH + n] = hh;
      ol[row * HH + n] = (_Float16)(hv - (float)hh);
      if constexpr (L == 2) {
        if (t == 63) p.out[row * 64 + n] = hv;
      }
    }
  }
}

// roles: [0,24) XPREP(s+2) | [24,152) XGEMM(s+1) | [152,280) L0rec(s)
//        | [280,344) L1(s-1) | [344,360) L2(s-2)
__global__ __launch_bounds__(256, 2) void cfc_step(Params p, int s) {
  const int bid = blockIdx.x;
  if (bid < 24)       { int t = s + 2; if (t >= 0 && t < 64) run_xprep(p, t, bid); }
  else if (bid < 152) { int t = s + 1; if (t >= 0 && t < 64) run_xgemm(p, t, bid - 24); }
  else if (bid < 280) { int t = s;     if (t >= 0 && t < 64) run_rec<0>(p, t, bid - 152); }
  else if (bid < 344) { int t = s - 1; if (t >= 0 && t < 64) run_rec<1>(p, t, bid - 280); }
  else                { int t = s - 2; if (t >= 0 && t < 64) run_rec<2>(p, t, bid - 344); }
}

__global__ void prep_w(const float* __restrict__ w, const float* __restrict__ mask,
                       _Float16* __restrict__ dst, int n) {
  int i = blockIdx.x * 256 + threadIdx.x;
  if (i < n) {
    float v = w[i];
    if (mask) v *= mask[i];
    dst[i] = (_Float16)v;
  }
}

__global__ void zero_kernel(unsigned* __restrict__ p, int n) {
  int i = blockIdx.x * 256 + threadIdx.x;
  if (i < n) p[i] = 0u;
}

extern "C" void kernel_launch(void* const* d_in, const int* in_sizes, int n_in,
                              void* d_out, int out_size, void* d_ws, size_t ws_size,
                              hipStream_t stream) {
  // ---- workspace layout (units: _Float16) ----
  _Float16* w0  = (_Float16*)d_ws;          // 4*512*1280 = 2,621,440
  _Float16* w1  = w0 + 2621440;             // 4*256*768  =   786,432
  _Float16* w2  = w1 + 786432;              // 4*64*320   =    81,920
  _Float16* xh0 = w2 + 81920;               // 512*768 per buffer
  _Float16* xl0 = xh0 + 393216;
  _Float16* xh1 = xl0 + 393216;
  _Float16* xl1 = xh1 + 393216;
  _Float16* hb  = xl1 + 393216;             // h region (zeroed)
  _Float16* h0h0 = hb;            _Float16* h0h1 = h0h0 + 262144;
  _Float16* h0l0 = h0h1 + 262144; _Float16* h0l1 = h0l0 + 262144;
  _Float16* h1h0 = h0l1 + 262144; _Float16* h1h1 = h1h0 + 131072;
  _Float16* h1l0 = h1h1 + 131072; _Float16* h1l1 = h1l0 + 131072;
  _Float16* h2h0 = h1l1 + 131072; _Float16* h2h1 = h2h0 + 32768;
  _Float16* h2l0 = h2h1 + 32768;  _Float16* h2l1 = h2l0 + 32768;
  float* xacc0 = (float*)(h2l1 + 32768);    // 512*2048 fp32 per buffer
  float* xacc1 = xacc0 + 1048576;           // total ws ≈ 21.9 MB

  // zero h ping-pong planes (ws is poisoned 0xAA before every call)
  const int h_uints = 1703936 / 2;
  zero_kernel<<<(h_uints + 255) / 256, 256, 0, stream>>>((unsigned*)hb, h_uints);

  const float* F = nullptr;
  auto in = [&](int i) { return (const float*)d_in[i]; };

  // weights -> fp16 (masked on ff1/ff2); gate order [ff1,ff2,ta,tb]
  prep_w<<<2560, 256, 0, stream>>>(in(2),  in(10), w0 + 0 * 655360, 655360);
  prep_w<<<2560, 256, 0, stream>>>(in(4),  in(10), w0 + 1 * 655360, 655360);
  prep_w<<<2560, 256, 0, stream>>>(in(6),  F,      w0 + 2 * 655360, 655360);
  prep_w<<<2560, 256, 0, stream>>>(in(8),  F,      w0 + 3 * 655360, 655360);
  prep_w<<<768,  256, 0, stream>>>(in(11), in(19), w1 + 0 * 196608, 196608);
  prep_w<<<768,  256, 0, stream>>>(in(13), in(19), w1 + 1 * 196608, 196608);
  prep_w<<<768,  256, 0, stream>>>(in(15), F,      w1 + 2 * 196608, 196608);
  prep_w<<<768,  256, 0, stream>>>(in(17), F,      w1 + 3 * 196608, 196608);
  prep_w<<<80,   256, 0, stream>>>(in(20), in(28), w2 + 0 * 20480,  20480);
  prep_w<<<80,   256, 0, stream>>>(in(22), in(28), w2 + 1 * 20480,  20480);
  prep_w<<<80,   256, 0, stream>>>(in(24), F,      w2 + 2 * 20480,  20480);
  prep_w<<<80,   256, 0, stream>>>(in(26), F,      w2 + 3 * 20480,  20480);

  Params p;
  p.base = in(0); p.visual = in(1);
  p.w0 = w0; p.w1 = w1; p.w2 = w2;
  p.b0f1 = in(3);  p.b0f2 = in(5);  p.b0ta = in(7);  p.b0tb = in(9);
  p.b1f1 = in(12); p.b1f2 = in(14); p.b1ta = in(16); p.b1tb = in(18);
  p.b2f1 = in(21); p.b2f2 = in(23); p.b2ta = in(25); p.b2tb = in(27);
  p.xh0 = xh0; p.xl0 = xl0; p.xh1 = xh1; p.xl1 = xl1;
  p.xacc0 = xacc0; p.xacc1 = xacc1;
  p.h0h0 = h0h0; p.h0h1 = h0h1; p.h0l0 = h0l0; p.h0l1 = h0l1;
  p.h1h0 = h1h0; p.h1h1 = h1h1; p.h1l0 = h1l0; p.h1l1 = h1l1;
  p.h2h0 = h2h0; p.h2h1 = h2h1; p.h2l0 = h2l0; p.h2l1 = h2l1;
  p.out = (float*)d_out;

  // pipeline: s=-2..65; XPREP t=s+2, XGEMM t=s+1, L0 t=s, L1 t=s-1, L2 t=s-2
  for (int s = -2; s < 66; ++s) {
    cfc_step<<<360, 256, 0, stream>>>(p, s);
  }
}